// Round 5
// baseline (361.023 us; speedup 1.0000x reference)
//
#include <hip/hip_runtime.h>

typedef unsigned short u16;
typedef unsigned int   u32;

#define BATCH 4
#define SEQ   8192
#define DIM   1024
#define FL    2048
#define TROW  10240   // padded time row: covers k up to 7936+2302 = 10238

// main kernel tiling (r5: counted-vmcnt ring, 3 waves/SIMD)
#define BM 256        // time rows per block (4 waves x 64 t-rows)
#define BN 64         // dims per block
#define BK 32         // staged K per stage (one 32-k MFMA step)
#define NSTAGE 72     // ceil((BM-1+FL)/BK) = 2303/32 -> 72
#define NBUF 4        // ring slots (prefetch distance 3)
#define WOFF 64       // W[w][j] = filt[w - WOFF + j]
#define NW   2272     // windows: read range [2, 2198]
#define WIN_HI 2110   // last active kk rel to wave base: 3*16+15 + FL-1

typedef float  f32x4  __attribute__((ext_vector_type(4)));
typedef __bf16 bf16x8 __attribute__((ext_vector_type(8)));
typedef short  s16x8  __attribute__((ext_vector_type(8)));

typedef const __attribute__((address_space(1))) void* gas_t;
typedef __attribute__((address_space(3))) void* las_t;

__device__ __forceinline__ u16 f2bf(float f) {
  u32 u = __float_as_uint(f);
  u += 0x7fffu + ((u >> 16) & 1u);   // round-to-nearest-even
  return (u16)(u >> 16);
}

// ---- pass 1: x[b][t][d] fp32 -> xT[b][d][t] bf16, zero-padded for t in [SEQ, TROW)
__global__ __launch_bounds__(256) void k_transpose(const float* __restrict__ x,
                                                   u16* __restrict__ xT) {
  __shared__ __align__(16) u16 sm[64 * 66];   // [t][d], stride 66 breaks bank conflicts
  const int bid = blockIdx.x;
  const int tb = bid % (TROW / 64);
  const int db = (bid / (TROW / 64)) % (DIM / 64);
  const int b  = bid / ((TROW / 64) * (DIM / 64));
  const int t0 = tb * 64, d0 = db * 64;
  const int tid = threadIdx.x;

  // load: 16 threads x float4 cover one 64-wide d row; 16 t-rows per sweep
  const int c4 = tid & 15;
  const int lt = tid >> 4;
  const float* xb = x + (size_t)b * SEQ * DIM + d0 + c4 * 4;
  #pragma unroll
  for (int s = 0; s < 64; s += 16) {
    const int tl = lt + s;
    const int t = t0 + tl;
    float4 v = make_float4(0.f, 0.f, 0.f, 0.f);
    if (t < SEQ) v = *(const float4*)(xb + (size_t)t * DIM);
    u32 p0 = (u32)f2bf(v.x) | ((u32)f2bf(v.y) << 16);
    u32 p1 = (u32)f2bf(v.z) | ((u32)f2bf(v.w) << 16);
    u32* dst = (u32*)&sm[tl * 66 + c4 * 4];
    dst[0] = p0;
    dst[1] = p1;
  }
  __syncthreads();
  // store: lane packs 8 consecutive t (16 B) per d row -> dwordx4 stores.
  const int q  = tid & 7;
  const int dl = tid >> 3;   // 0..31
  u16* xo = xT + ((size_t)b * DIM + d0) * TROW + t0 + 8 * q;
  #pragma unroll
  for (int s = 0; s < 2; ++s) {
    const int d = dl + 32 * s;
    u32 w[4];
    #pragma unroll
    for (int h = 0; h < 4; ++h) {
      w[h] = (u32)sm[(8 * q + 2 * h) * 66 + d] |
             ((u32)sm[(8 * q + 2 * h + 1) * 66 + d] << 16);
    }
    *(uint4*)(xo + (size_t)d * TROW) = *(const uint4*)w;
  }
}

// ---- pass 2: banded-Toeplitz MFMA conv.
// Out[t,d] = sum_k filt[k-t] * x[k,d].  A = Toeplitz (M=t), B = xT (N=d), K = k.
//
// Geometry (r4, kept): 256-thread blocks, 4 waves = 4 t-groups, wave tile
// 64(t) x 64(d) = 4 m x 4 n of 16x16x32 MFMA; acc[4][4] (64 AGPR) + ~68 VGPR
// -> 3 waves/SIMD; LDS 52.7 KB -> 3 blocks/CU. Rolling A across stages:
// A(mt)@stage == A(mt-2)@(stage-1) -> only 2 Wb reads per 16 MFMAs.
//
// Pipeline (r5, NEW): r4 kept MfmaUtil pinned at 43% because __syncthreads
// drains vmcnt(0) every stage -> full staging latency (~2-3K cyc) exposed
// per stage in EVERY block. Fix is m201/m218's counted-vmcnt ring:
//   BK=32, NBUF=4 slots (4 KB each), 1 global_load_lds per wave per stage,
//   prefetch distance 3. Stage top: s_waitcnt vmcnt(2) [clobberless asm --
//   a "memory" clobber forces the backend to drain, which nulled r1] +
//   raw s_barrier, fenced by sched_barrier(0) on both sides (rule #18).
//   Steady state keeps 2 loads in flight ACROSS the barrier; staging
//   latency now amortizes over 3 stages of MFMA.
// Slot overwrite safety: slot (st+3)&3 == (st-1)&3; its readers finished
// before barrier(st) (their data was consumed by MFMAs pre-barrier).
__global__ __launch_bounds__(256, 3) void k_conv(const u16* __restrict__ xT,
                                                 const float* __restrict__ filt,
                                                 float* __restrict__ out) {
  __shared__ __align__(16) u16 Wb[NW * 8];          // filter windows, 35.5 KB
  __shared__ __align__(16) u16 Xs[NBUF][BN * BK];   // staged x ring, 4 x 4 KB

  const int bid = blockIdx.x;
  const int tb = bid & 31;
  const int db = (bid >> 5) & 15;
  const int b  = bid >> 9;
  const int t0 = tb * BM;
  const int d0 = db * BN;

  const int tid  = threadIdx.x;
  const int wid  = tid >> 6;    // 0..3
  const int lane = tid & 63;
  const int quad = lane >> 4;
  const int lq   = lane & 15;
  const int Tw   = wid * 64;    // wave's time base within block

  // staging decode: physical chunk p (0..255) -> row d = p>>2, k-chunk
  // kc = (p&3) ^ ((d>>1)&3). The (d>>1) XOR gives the read pattern an
  // 8-row period so each 8-lane ds_read_b128 group covers all 32 banks
  // (conflict-free); matches global_load_lds's "base + lane*16" placement.
  const u16* xrow = xT + ((size_t)b * DIM + d0) * TROW + t0;
  const int p0 = wid * 64 + lane;
  const int ds0 = p0 >> 2, kc0 = (p0 & 3) ^ ((ds0 >> 1) & 3);
  const u16* gp0 = xrow + (size_t)ds0 * TROW + kc0 * 8;

  // prologue: prefetch stages 0..2 into slots 0..2 (1 load/wave/stage),
  // issued BEFORE the Wb build so HBM latency overlaps the VALU work.
  #pragma unroll
  for (int p = 0; p < 3; ++p) {
    __builtin_amdgcn_global_load_lds((gas_t)(gp0 + p * BK),
                                     (las_t)&Xs[p][wid * 512], 16, 0, 0);
  }

  // build filter windows: Wb[w][j] = bf16(filt[w - WOFF + j]), zeros outside [0,FL)
  for (int w = tid; w < NW; w += 256) {
    const int base = w - WOFF;
    u32 pk[4];
    #pragma unroll
    for (int h = 0; h < 4; ++h) {
      const int i0 = base + 2 * h;
      const int i1 = i0 + 1;
      const float v0 = (i0 >= 0 && i0 < FL) ? filt[i0] : 0.f;
      const float v1 = (i1 >= 0 && i1 < FL) ? filt[i1] : 0.f;
      pk[h] = (u32)f2bf(v0) | ((u32)f2bf(v1) << 16);
    }
    u32* dst = (u32*)&Wb[w * 8];
    dst[0] = pk[0]; dst[1] = pk[1]; dst[2] = pk[2]; dst[3] = pk[3];
  }

  f32x4 acc[4][4];
  const f32x4 fz = {0.f, 0.f, 0.f, 0.f};
  #pragma unroll
  for (int i = 0; i < 4; ++i)
    #pragma unroll
    for (int j = 0; j < 4; ++j) acc[i][j] = fz;

  const s16x8 sz = {0, 0, 0, 0, 0, 0, 0, 0};
  bf16x8 roll0 = __builtin_bit_cast(bf16x8, sz);
  bf16x8 roll1 = roll0;

  const int wconst = quad * 8 - Tw - lq + WOFF;
  const int kkLo = Tw - 31;        // active: kk+31 >= Tw
  const int kkHi = Tw + WIN_HI;    // active: kk <= Tw + 2110

  for (int st = 0; st < NSTAGE; ++st) {
    // Barrier protocol:
    //  st==0: full __syncthreads -- drains Wb ds_writes AND the 3 prologue
    //         prefetches (one-time cost; stages 1,2 arrive pre-drained).
    //  st>=1: counted wait. Outstanding loads at stage top: st, st+1, st+2
    //         (1 each, FIFO) -> vmcnt(2) completes stage st's. NO memory
    //         clobber (that forces a backend drain); sched_barrier(0) pins
    //         the ds_reads/MFMAs on each side instead.
    if (st == 0) {
      __syncthreads();
    } else {
      __builtin_amdgcn_sched_barrier(0);
      if (st + 2 < NSTAGE)      asm volatile("s_waitcnt vmcnt(2)");
      else if (st + 1 < NSTAGE) asm volatile("s_waitcnt vmcnt(1)");
      else                      asm volatile("s_waitcnt vmcnt(0)");
      __builtin_amdgcn_sched_barrier(0);
      __builtin_amdgcn_s_barrier();
      __builtin_amdgcn_sched_barrier(0);
    }
    // prefetch stage st+3 into ring slot (st+3)&3 == (st-1)&3 (safe: its
    // stage-(st-1) readers finished before the barrier above).
    if (st + 3 < NSTAGE) {   // block-uniform branch
      __builtin_amdgcn_global_load_lds((gas_t)(gp0 + (st + 3) * BK),
                                       (las_t)&Xs[(st + 3) & (NBUF - 1)][wid * 512],
                                       16, 0, 0);
    }
    const int kk = st * BK;
    if (kk >= kkLo && kk <= kkHi) {   // wave-uniform branch
      const u16* Xc = &Xs[st & (NBUF - 1)][0];
      bf16x8 bfr[4];
      #pragma unroll
      for (int nt = 0; nt < 4; ++nt) {
        const int dl = nt * 16 + lq;
        const int kc = quad ^ ((dl >> 1) & 3);
        bfr[nt] = *(const bf16x8*)&Xc[(dl * 4 + kc) * 8];
      }
      const int w0 = kk + wconst;
      const bf16x8 a0 = *(const bf16x8*)&Wb[w0 * 8];
      const bf16x8 a1 = *(const bf16x8*)&Wb[(w0 - 16) * 8];
      __builtin_amdgcn_s_setprio(1);   // T5: MFMA-phase wave wins arbitration
      #pragma unroll
      for (int nt = 0; nt < 4; ++nt) {
        acc[0][nt] = __builtin_amdgcn_mfma_f32_16x16x32_bf16(a0,    bfr[nt], acc[0][nt], 0, 0, 0);
        acc[1][nt] = __builtin_amdgcn_mfma_f32_16x16x32_bf16(a1,    bfr[nt], acc[1][nt], 0, 0, 0);
        acc[2][nt] = __builtin_amdgcn_mfma_f32_16x16x32_bf16(roll0, bfr[nt], acc[2][nt], 0, 0, 0);
        acc[3][nt] = __builtin_amdgcn_mfma_f32_16x16x32_bf16(roll1, bfr[nt], acc[3][nt], 0, 0, 0);
      }
      __builtin_amdgcn_s_setprio(0);
      roll0 = a0; roll1 = a1;
    }
  }

  // epilogue: C/D layout col = lane&15 (d), row = quad*4 + reg (t)
  float* ob = out + ((size_t)b * SEQ + t0 + Tw) * DIM + d0;
  #pragma unroll
  for (int mt = 0; mt < 4; ++mt) {
    #pragma unroll
    for (int nt = 0; nt < 4; ++nt) {
      #pragma unroll
      for (int r = 0; r < 4; ++r) {
        ob[(size_t)(mt * 16 + quad * 4 + r) * DIM + nt * 16 + lq] = acc[mt][nt][r];
      }
    }
  }
}

extern "C" void kernel_launch(void* const* d_in, const int* in_sizes, int n_in,
                              void* d_out, int out_size, void* d_ws, size_t ws_size,
                              hipStream_t stream) {
  const float* x    = (const float*)d_in[0];
  const float* filt = (const float*)d_in[1];
  float* out = (float*)d_out;
  u16* xT = (u16*)d_ws;   // needs 4*1024*10240*2 = 83.9 MB of workspace
  (void)in_sizes; (void)n_in; (void)out_size; (void)ws_size;

  k_transpose<<<BATCH * (TROW / 64) * (DIM / 64), 256, 0, stream>>>(x, xT);
  k_conv<<<BATCH * 32 * 16, 256, 0, stream>>>(xT, filt, out);
}